// Round 1
// baseline (474.641 us; speedup 1.0000x reference)
//
#include <hip/hip_runtime.h>
#include <hip/hip_bf16.h>
#include <stdint.h>

typedef __attribute__((ext_vector_type(4))) float floatx4;
typedef __attribute__((ext_vector_type(8))) short shortx8;

#define NTOK 2048
#define DMODEL 1024
#define NHEAD 16
#define DHEAD 64
#define BATCH 2

static __device__ __forceinline__ unsigned short f2bf(float f) {
    union { float f; unsigned int u; } v; v.f = f;
    return (unsigned short)((v.u + 0x7FFFu + ((v.u >> 16) & 1u)) >> 16);
}

static __device__ __forceinline__ floatx4 mfma16(shortx8 a, shortx8 b, floatx4 c) {
    return __builtin_amdgcn_mfma_f32_16x16x32_bf16(a, b, c, 0, 0, 0);
}

static __device__ __forceinline__ void gl_lds16(const unsigned short* g, unsigned short* l) {
    __builtin_amdgcn_global_load_lds(
        (const __attribute__((address_space(1))) unsigned int*)g,
        (__attribute__((address_space(3))) unsigned int*)l, 16, 0, 0);
}

// ---------------- cast f32 -> bf16 for query/key/value ----------------
__global__ void cast_x_kernel(const float* __restrict__ q, const float* __restrict__ k,
                              const float* __restrict__ v,
                              unsigned short* __restrict__ oq, unsigned short* __restrict__ ok,
                              unsigned short* __restrict__ ov) {
    const float* src = blockIdx.y == 0 ? q : (blockIdx.y == 1 ? k : v);
    unsigned short* dst = blockIdx.y == 0 ? oq : (blockIdx.y == 1 ? ok : ov);
    int i = (blockIdx.x * 256 + threadIdx.x) * 8;
    floatx4 a = *(const floatx4*)(src + i);
    floatx4 b = *(const floatx4*)(src + i + 4);
    union { shortx8 s; unsigned short u[8]; } o;
    o.u[0] = f2bf(a[0]); o.u[1] = f2bf(a[1]); o.u[2] = f2bf(a[2]); o.u[3] = f2bf(a[3]);
    o.u[4] = f2bf(b[0]); o.u[5] = f2bf(b[1]); o.u[6] = f2bf(b[2]); o.u[7] = f2bf(b[3]);
    *(shortx8*)(dst + i) = o.s;
}

// ---------------- transpose + cast W [K,N] f32 -> Wt [N,K] bf16 ----------------
__global__ void transpose_w_kernel(const float* __restrict__ wq, const float* __restrict__ wk,
                                   const float* __restrict__ wv,
                                   unsigned short* __restrict__ tq, unsigned short* __restrict__ tk,
                                   unsigned short* __restrict__ tv) {
    __shared__ float tile[32][33];
    const float* W = blockIdx.z == 0 ? wq : (blockIdx.z == 1 ? wk : wv);
    unsigned short* T = blockIdx.z == 0 ? tq : (blockIdx.z == 1 ? tk : tv);
    int tx = threadIdx.x, ty = threadIdx.y;
    int bx = blockIdx.x, by = blockIdx.y;
#pragma unroll
    for (int j = 0; j < 4; j++)
        tile[ty + j * 8][tx] = W[(by * 32 + ty + j * 8) * DMODEL + bx * 32 + tx];
    __syncthreads();
#pragma unroll
    for (int j = 0; j < 4; j++)
        T[(bx * 32 + ty + j * 8) * DMODEL + by * 32 + tx] = f2bf(tile[tx][ty + j * 8]);
}

// ---------------- projection GEMM: C = X @ W + b, head-split bf16 outputs ----------------
// X bf16 [4096,1024], Wt bf16 [1024(N),1024(K)], out: z<2 -> [B,H,N,64], z==2 -> [B,H,64,N]
__launch_bounds__(256)
__global__ void proj_gemm_kernel(const unsigned short* __restrict__ xq, const unsigned short* __restrict__ xk,
                                 const unsigned short* __restrict__ xv,
                                 const unsigned short* __restrict__ tq, const unsigned short* __restrict__ tk,
                                 const unsigned short* __restrict__ tv,
                                 const float* __restrict__ bq, const float* __restrict__ bk,
                                 const float* __restrict__ bv,
                                 unsigned short* __restrict__ qh, unsigned short* __restrict__ kh,
                                 unsigned short* __restrict__ vt) {
    int z = blockIdx.z;
    const unsigned short* X = z == 0 ? xq : (z == 1 ? xk : xv);
    const unsigned short* W = z == 0 ? tq : (z == 1 ? tk : tv);
    const float* bias = z == 0 ? bq : (z == 1 ? bk : bv);

    __shared__ unsigned short As[128 * 32];
    __shared__ unsigned short Bs[128 * 32];

    int t = threadIdx.x;
    int lane = t & 63, w = t >> 6;
    int wr = w >> 1, wc = w & 1;
    int r = lane & 15, g = lane >> 4;
    int m0 = blockIdx.y * 128, n0 = blockIdx.x * 128;

    floatx4 acc[4][4];
#pragma unroll
    for (int i = 0; i < 4; i++)
#pragma unroll
        for (int j = 0; j < 4; j++) acc[i][j] = (floatx4){0.f, 0.f, 0.f, 0.f};

    for (int kt = 0; kt < DMODEL; kt += 32) {
#pragma unroll
        for (int i = 0; i < 2; i++) {
            int idx = t + 256 * i;
            int row = idx >> 2, c8 = (idx & 3) * 8;
            gl_lds16(X + (size_t)(m0 + row) * DMODEL + kt + c8, As + idx * 8);
            gl_lds16(W + (size_t)(n0 + row) * DMODEL + kt + c8, Bs + idx * 8);
        }
        __syncthreads();
        shortx8 a[4], b[4];
#pragma unroll
        for (int f = 0; f < 4; f++) {
            a[f] = *(const shortx8*)(As + (wr * 64 + f * 16 + r) * 32 + g * 8);
            b[f] = *(const shortx8*)(Bs + (wc * 64 + f * 16 + r) * 32 + g * 8);
        }
#pragma unroll
        for (int fm = 0; fm < 4; fm++)
#pragma unroll
            for (int fn = 0; fn < 4; fn++)
                acc[fm][fn] = mfma16(a[fm], b[fn], acc[fm][fn]);
        __syncthreads();
    }

    unsigned short* dstQK = (z == 0) ? qh : kh;
#pragma unroll
    for (int fm = 0; fm < 4; fm++) {
#pragma unroll
        for (int fn = 0; fn < 4; fn++) {
            int n = n0 + wc * 64 + fn * 16 + r;
            float bval = bias[n];
            int h = n >> 6, d = n & 63;
#pragma unroll
            for (int reg = 0; reg < 4; reg++) {
                int m = m0 + wr * 64 + fm * 16 + g * 4 + reg;
                int bb = m >> 11, tok = m & 2047;
                unsigned short o = f2bf(acc[fm][fn][reg] + bval);
                if (z < 2)
                    dstQK[(((size_t)(bb * NHEAD + h) * NTOK + tok) * DHEAD) + d] = o;
                else
                    vt[(((size_t)(bb * NHEAD + h) * DHEAD + d) * NTOK) + tok] = o;
            }
        }
    }
}

// ---------------- fused attention: scores -> softmax -> attn out + context ----------------
// Qh,Kh: [B*H, 2048, 64] bf16 ; Vt: [B*H, 64, 2048] bf16
// ctx: [B, 2048, 1024] f32 ; attn: [B*H, 2048, 2048] f32
__launch_bounds__(256)
__global__ void attn_kernel(const unsigned short* __restrict__ Qh,
                            const unsigned short* __restrict__ Kh,
                            const unsigned short* __restrict__ Vt,
                            float* __restrict__ ctx, float* __restrict__ attn) {
    __shared__ unsigned short ew[4][16][40];  // per-wave P-tile, padded (+8) for bank spread

    int t = threadIdx.x;
    int lane = t & 63, w = t >> 6;
    int r = lane & 15, g = lane >> 4;
    int bh = blockIdx.y;
    int q0 = blockIdx.x * 64 + w * 16;

    const unsigned short* Qp = Qh + ((size_t)bh * NTOK + q0) * DHEAD;
    const unsigned short* Kp = Kh + (size_t)bh * NTOK * DHEAD;
    const unsigned short* Vp = Vt + (size_t)bh * DHEAD * NTOK;

    // Q fragments (persist in registers): rows r, d = c*32 + g*8 + i
    shortx8 qf0 = *(const shortx8*)(Qp + r * DHEAD + g * 8);
    shortx8 qf1 = *(const shortx8*)(Qp + r * DHEAD + 32 + g * 8);

    // ---- pass 1: row sums of exp(score) ----
    float sum[4] = {0.f, 0.f, 0.f, 0.f};
    for (int kk = 0; kk < NTOK; kk += 16) {
        shortx8 k0 = *(const shortx8*)(Kp + (size_t)(kk + r) * DHEAD + g * 8);
        shortx8 k1 = *(const shortx8*)(Kp + (size_t)(kk + r) * DHEAD + 32 + g * 8);
        floatx4 s = (floatx4){0.f, 0.f, 0.f, 0.f};
        s = mfma16(qf0, k0, s);
        s = mfma16(qf1, k1, s);
#pragma unroll
        for (int reg = 0; reg < 4; reg++) sum[reg] += __expf(0.125f * s[reg]);
    }
#pragma unroll
    for (int m = 1; m < 16; m <<= 1)
#pragma unroll
        for (int reg = 0; reg < 4; reg++) sum[reg] += __shfl_xor(sum[reg], m, 64);
    float inv[4];
#pragma unroll
    for (int reg = 0; reg < 4; reg++) inv[reg] = 1.0f / sum[reg];

    // ---- pass 2: recompute, write normalized attn, accumulate PV ----
    floatx4 pv[4];
#pragma unroll
    for (int i = 0; i < 4; i++) pv[i] = (floatx4){0.f, 0.f, 0.f, 0.f};
    unsigned short(*ewp)[40] = ew[w];

    for (int kk = 0; kk < NTOK; kk += 32) {
#pragma unroll
        for (int half = 0; half < 2; half++) {
            int kt = kk + half * 16;
            shortx8 k0 = *(const shortx8*)(Kp + (size_t)(kt + r) * DHEAD + g * 8);
            shortx8 k1 = *(const shortx8*)(Kp + (size_t)(kt + r) * DHEAD + 32 + g * 8);
            floatx4 s = (floatx4){0.f, 0.f, 0.f, 0.f};
            s = mfma16(qf0, k0, s);
            s = mfma16(qf1, k1, s);
#pragma unroll
            for (int reg = 0; reg < 4; reg++) {
                float e = __expf(0.125f * s[reg]) * inv[reg];
                attn[((size_t)bh * NTOK + (q0 + g * 4 + reg)) * NTOK + kt + r] = e;
                ewp[g * 4 + reg][half * 16 + r] = f2bf(e);
            }
        }
        // per-wave LDS transpose round-trip (same wave: DS in-order, no barrier)
        shortx8 pa = *(const shortx8*)(&ewp[r][g * 8]);
#pragma unroll
        for (int dt = 0; dt < 4; dt++) {
            shortx8 bvf = *(const shortx8*)(Vp + (size_t)(dt * 16 + r) * NTOK + kk + g * 8);
            pv[dt] = mfma16(pa, bvf, pv[dt]);
        }
    }

    int bb = bh >> 4, h = bh & 15;
#pragma unroll
    for (int dt = 0; dt < 4; dt++)
#pragma unroll
        for (int reg = 0; reg < 4; reg++) {
            int tok = q0 + g * 4 + reg;
            ctx[((size_t)(bb * NTOK + tok)) * DMODEL + h * DHEAD + dt * 16 + r] = pv[dt][reg];
        }
}

extern "C" void kernel_launch(void* const* d_in, const int* in_sizes, int n_in,
                              void* d_out, int out_size, void* d_ws, size_t ws_size,
                              hipStream_t stream) {
    const float* query = (const float*)d_in[0];
    const float* key   = (const float*)d_in[1];
    const float* value = (const float*)d_in[2];
    const float* Wq = (const float*)d_in[3];
    const float* bq = (const float*)d_in[4];
    const float* Wk = (const float*)d_in[5];
    const float* bk = (const float*)d_in[6];
    const float* Wv = (const float*)d_in[7];
    const float* bv = (const float*)d_in[8];

    const size_t NX = (size_t)BATCH * NTOK * DMODEL;  // 4194304
    const size_t NW = (size_t)DMODEL * DMODEL;        // 1048576

    unsigned short* ws = (unsigned short*)d_ws;
    unsigned short* Xq = ws;
    unsigned short* Xk = Xq + NX;
    unsigned short* Xv = Xk + NX;
    unsigned short* Tq = Xv + NX;
    unsigned short* Tk = Tq + NW;
    unsigned short* Tv = Tk + NW;
    unsigned short* Qh = Tv + NW;
    unsigned short* Kh = Qh + NX;
    unsigned short* Vt = Kh + NX;

    float* ctx = (float*)d_out;
    float* attn = ctx + NX;

    cast_x_kernel<<<dim3(2048, 3), 256, 0, stream>>>(query, key, value, Xq, Xk, Xv);
    transpose_w_kernel<<<dim3(32, 32, 3), dim3(32, 8), 0, stream>>>(Wq, Wk, Wv, Tq, Tk, Tv);
    proj_gemm_kernel<<<dim3(8, 32, 3), 256, 0, stream>>>(Xq, Xk, Xv, Tq, Tk, Tv,
                                                         bq, bk, bv, Qh, Kh, Vt);
    attn_kernel<<<dim3(32, 32), 256, 0, stream>>>(Qh, Kh, Vt, ctx, attn);
}

// Round 2
// 473.362 us; speedup vs baseline: 1.0027x; 1.0027x over previous
//
#include <hip/hip_runtime.h>
#include <hip/hip_bf16.h>
#include <stdint.h>

typedef __attribute__((ext_vector_type(4))) float floatx4;
typedef __attribute__((ext_vector_type(8))) short shortx8;

#define NTOK 2048
#define DMODEL 1024
#define NHEAD 16
#define DHEAD 64
#define BATCH 2

static __device__ __forceinline__ unsigned short f2bf(float f) {
    union { float f; unsigned int u; } v; v.f = f;
    return (unsigned short)((v.u + 0x7FFFu + ((v.u >> 16) & 1u)) >> 16);
}

static __device__ __forceinline__ floatx4 mfma16(shortx8 a, shortx8 b, floatx4 c) {
    return __builtin_amdgcn_mfma_f32_16x16x32_bf16(a, b, c, 0, 0, 0);
}

static __device__ __forceinline__ void gl_lds16(const unsigned short* g, unsigned short* l) {
    __builtin_amdgcn_global_load_lds(
        (const __attribute__((address_space(1))) unsigned int*)g,
        (__attribute__((address_space(3))) unsigned int*)l, 16, 0, 0);
}

// ---------------- cast f32 -> bf16 for query/key/value ----------------
__global__ void cast_x_kernel(const float* __restrict__ q, const float* __restrict__ k,
                              const float* __restrict__ v,
                              unsigned short* __restrict__ oq, unsigned short* __restrict__ ok,
                              unsigned short* __restrict__ ov) {
    const float* src = blockIdx.y == 0 ? q : (blockIdx.y == 1 ? k : v);
    unsigned short* dst = blockIdx.y == 0 ? oq : (blockIdx.y == 1 ? ok : ov);
    int i = (blockIdx.x * 256 + threadIdx.x) * 8;
    floatx4 a = *(const floatx4*)(src + i);
    floatx4 b = *(const floatx4*)(src + i + 4);
    union { shortx8 s; unsigned short u[8]; } o;
    o.u[0] = f2bf(a[0]); o.u[1] = f2bf(a[1]); o.u[2] = f2bf(a[2]); o.u[3] = f2bf(a[3]);
    o.u[4] = f2bf(b[0]); o.u[5] = f2bf(b[1]); o.u[6] = f2bf(b[2]); o.u[7] = f2bf(b[3]);
    *(shortx8*)(dst + i) = o.s;
}

// ---------------- transpose + cast W [K,N] f32 -> Wt [N,K] bf16 ----------------
__global__ void transpose_w_kernel(const float* __restrict__ wq, const float* __restrict__ wk,
                                   const float* __restrict__ wv,
                                   unsigned short* __restrict__ tq, unsigned short* __restrict__ tk,
                                   unsigned short* __restrict__ tv) {
    __shared__ float tile[32][33];
    const float* W = blockIdx.z == 0 ? wq : (blockIdx.z == 1 ? wk : wv);
    unsigned short* T = blockIdx.z == 0 ? tq : (blockIdx.z == 1 ? tk : tv);
    int tx = threadIdx.x, ty = threadIdx.y;
    int bx = blockIdx.x, by = blockIdx.y;
#pragma unroll
    for (int j = 0; j < 4; j++)
        tile[ty + j * 8][tx] = W[(by * 32 + ty + j * 8) * DMODEL + bx * 32 + tx];
    __syncthreads();
#pragma unroll
    for (int j = 0; j < 4; j++)
        T[(bx * 32 + ty + j * 8) * DMODEL + by * 32 + tx] = f2bf(tile[tx][ty + j * 8]);
}

// ---------------- projection GEMM: C = X @ W + b, head-split bf16 outputs ----------------
__launch_bounds__(256)
__global__ void proj_gemm_kernel(const unsigned short* __restrict__ xq, const unsigned short* __restrict__ xk,
                                 const unsigned short* __restrict__ xv,
                                 const unsigned short* __restrict__ tq, const unsigned short* __restrict__ tk,
                                 const unsigned short* __restrict__ tv,
                                 const float* __restrict__ bq, const float* __restrict__ bk,
                                 const float* __restrict__ bv,
                                 unsigned short* __restrict__ qh, unsigned short* __restrict__ kh,
                                 unsigned short* __restrict__ vt) {
    int z = blockIdx.z;
    const unsigned short* X = z == 0 ? xq : (z == 1 ? xk : xv);
    const unsigned short* W = z == 0 ? tq : (z == 1 ? tk : tv);
    const float* bias = z == 0 ? bq : (z == 1 ? bk : bv);

    __shared__ unsigned short As[128 * 32];
    __shared__ unsigned short Bs[128 * 32];

    int t = threadIdx.x;
    int lane = t & 63, w = t >> 6;
    int wr = w >> 1, wc = w & 1;
    int r = lane & 15, g = lane >> 4;
    int m0 = blockIdx.y * 128, n0 = blockIdx.x * 128;

    floatx4 acc[4][4];
#pragma unroll
    for (int i = 0; i < 4; i++)
#pragma unroll
        for (int j = 0; j < 4; j++) acc[i][j] = (floatx4){0.f, 0.f, 0.f, 0.f};

    for (int kt = 0; kt < DMODEL; kt += 32) {
#pragma unroll
        for (int i = 0; i < 2; i++) {
            int idx = t + 256 * i;
            int row = idx >> 2, c8 = (idx & 3) * 8;
            gl_lds16(X + (size_t)(m0 + row) * DMODEL + kt + c8, As + idx * 8);
            gl_lds16(W + (size_t)(n0 + row) * DMODEL + kt + c8, Bs + idx * 8);
        }
        __syncthreads();
        shortx8 a[4], b[4];
#pragma unroll
        for (int f = 0; f < 4; f++) {
            a[f] = *(const shortx8*)(As + (wr * 64 + f * 16 + r) * 32 + g * 8);
            b[f] = *(const shortx8*)(Bs + (wc * 64 + f * 16 + r) * 32 + g * 8);
        }
#pragma unroll
        for (int fm = 0; fm < 4; fm++)
#pragma unroll
            for (int fn = 0; fn < 4; fn++)
                acc[fm][fn] = mfma16(a[fm], b[fn], acc[fm][fn]);
        __syncthreads();
    }

    unsigned short* dstQK = (z == 0) ? qh : kh;
#pragma unroll
    for (int fm = 0; fm < 4; fm++) {
#pragma unroll
        for (int fn = 0; fn < 4; fn++) {
            int n = n0 + wc * 64 + fn * 16 + r;
            float bval = bias[n];
            int h = n >> 6, d = n & 63;
#pragma unroll
            for (int reg = 0; reg < 4; reg++) {
                int m = m0 + wr * 64 + fm * 16 + g * 4 + reg;
                int bb = m >> 11, tok = m & 2047;
                unsigned short o = f2bf(acc[fm][fn][reg] + bval);
                if (z < 2)
                    dstQK[(((size_t)(bb * NHEAD + h) * NTOK + tok) * DHEAD) + d] = o;
                else
                    vt[(((size_t)(bb * NHEAD + h) * DHEAD + d) * NTOK) + tok] = o;
            }
        }
    }
}

// ---------------- fused attention (swapped-operand layout) ----------------
// Qh,Kh: [B*H, 2048, 64] bf16 ; Vt: [B*H, 64, 2048] bf16
// ctx: [B, 2048, 1024] f32 ; attn: [B*H, 2048, 2048] f32
// Score MFMA: mfma(K_frag, Q_frag) -> lane holds q = lane&15, k = g*4 + reg (4 consecutive k).
// PV MFMA:    mfma(V_frag, P_frag) -> lane holds q = lane&15, d = g*4 + reg.
__launch_bounds__(256)
__global__ void attn_kernel(const unsigned short* __restrict__ Qh,
                            const unsigned short* __restrict__ Kh,
                            const unsigned short* __restrict__ Vt,
                            float* __restrict__ ctx, float* __restrict__ attn) {
    __shared__ __align__(16) unsigned int plds[4][16][20];  // per-wave P tile, 32 dwords/row used (16 cols) + pad

    int t = threadIdx.x;
    int lane = t & 63, w = t >> 6;
    int r = lane & 15, g = lane >> 4;
    int bh = blockIdx.y;
    int q0 = blockIdx.x * 64 + w * 16;

    const unsigned short* Qp = Qh + ((size_t)bh * NTOK + q0) * DHEAD;
    const unsigned short* Kp = Kh + (size_t)bh * NTOK * DHEAD;
    const unsigned short* Vp = Vt + (size_t)bh * DHEAD * NTOK;

    // Q fragments (B-operand): lane supplies col q=r, d = g*8..g*8+7 (+32 for second half)
    shortx8 qf0 = *(const shortx8*)(Qp + r * DHEAD + g * 8);
    shortx8 qf1 = *(const shortx8*)(Qp + r * DHEAD + 32 + g * 8);

    const floatx4 zero = (floatx4){0.f, 0.f, 0.f, 0.f};

    // ---- pass 1: row sums of exp(score) ----
    float sm[4] = {0.f, 0.f, 0.f, 0.f};
#pragma unroll 2
    for (int kk = 0; kk < NTOK; kk += 16) {
        shortx8 kf0 = *(const shortx8*)(Kp + (size_t)(kk + r) * DHEAD + g * 8);
        shortx8 kf1 = *(const shortx8*)(Kp + (size_t)(kk + r) * DHEAD + 32 + g * 8);
        floatx4 sc = mfma16(kf0, qf0, zero);
        sc = mfma16(kf1, qf1, sc);
#pragma unroll
        for (int reg = 0; reg < 4; reg++) sm[reg] += __expf(0.125f * sc[reg]);
    }
    float tot = (sm[0] + sm[1]) + (sm[2] + sm[3]);
    tot += __shfl_xor(tot, 16, 64);
    tot += __shfl_xor(tot, 32, 64);
    float inv = 1.0f / tot;

    // ---- pass 2: recompute, write normalized attn (float4), accumulate PV ----
    floatx4 pv[4];
#pragma unroll
    for (int i = 0; i < 4; i++) pv[i] = zero;

    unsigned int(*pw)[20] = plds[w];
    const int xr = (r & 3) << 2;  // XOR swizzle on dword column (bits 2-3)
    float* attn_row = attn + ((size_t)bh * NTOK + q0 + r) * NTOK;

#pragma unroll 2
    for (int kk = 0; kk < NTOK; kk += 32) {
#pragma unroll
        for (int t2 = 0; t2 < 2; t2++) {
            int kt = kk + t2 * 16;
            shortx8 kf0 = *(const shortx8*)(Kp + (size_t)(kt + r) * DHEAD + g * 8);
            shortx8 kf1 = *(const shortx8*)(Kp + (size_t)(kt + r) * DHEAD + 32 + g * 8);
            floatx4 sc = mfma16(kf0, qf0, zero);
            sc = mfma16(kf1, qf1, sc);
            float e0 = __expf(0.125f * sc[0]) * inv;
            float e1 = __expf(0.125f * sc[1]) * inv;
            float e2 = __expf(0.125f * sc[2]) * inv;
            float e3 = __expf(0.125f * sc[3]) * inv;
            floatx4 st = (floatx4){e0, e1, e2, e3};
            *(floatx4*)(attn_row + kt + g * 4) = st;
            unsigned int p01, p23;
            asm("v_cvt_pk_bf16_f32 %0, %1, %2" : "=v"(p01) : "v"(e0), "v"(e1));
            asm("v_cvt_pk_bf16_f32 %0, %1, %2" : "=v"(p23) : "v"(e2), "v"(e3));
            pw[r][(t2 * 8 + 2 * g) ^ xr] = p01;
            pw[r][(t2 * 8 + 2 * g + 1) ^ xr] = p23;
        }
        // P fragment: lane (r,g) reads P[q=r][k = g*8..g*8+7] (dwords g*4..g*4+3, XOR-swizzled)
        shortx8 pb = *(const shortx8*)((const unsigned short*)&pw[r][(g * 4) ^ xr]);
#pragma unroll
        for (int dt = 0; dt < 4; dt++) {
            shortx8 va = *(const shortx8*)(Vp + (size_t)(dt * 16 + r) * NTOK + kk + g * 8);
            pv[dt] = mfma16(va, pb, pv[dt]);
        }
    }

    int bb = bh >> 4, h = bh & 15;
    float* ctx_row = ctx + ((size_t)(bb * NTOK + q0 + r)) * DMODEL + h * DHEAD;
#pragma unroll
    for (int dt = 0; dt < 4; dt++)
        *(floatx4*)(ctx_row + dt * 16 + g * 4) = pv[dt];
}

extern "C" void kernel_launch(void* const* d_in, const int* in_sizes, int n_in,
                              void* d_out, int out_size, void* d_ws, size_t ws_size,
                              hipStream_t stream) {
    const float* query = (const float*)d_in[0];
    const float* key   = (const float*)d_in[1];
    const float* value = (const float*)d_in[2];
    const float* Wq = (const float*)d_in[3];
    const float* bq = (const float*)d_in[4];
    const float* Wk = (const float*)d_in[5];
    const float* bk = (const float*)d_in[6];
    const float* Wv = (const float*)d_in[7];
    const float* bv = (const float*)d_in[8];

    const size_t NX = (size_t)BATCH * NTOK * DMODEL;  // 4194304
    const size_t NW = (size_t)DMODEL * DMODEL;        // 1048576

    unsigned short* ws = (unsigned short*)d_ws;
    unsigned short* Xq = ws;
    unsigned short* Xk = Xq + NX;
    unsigned short* Xv = Xk + NX;
    unsigned short* Tq = Xv + NX;
    unsigned short* Tk = Tq + NW;
    unsigned short* Tv = Tk + NW;
    unsigned short* Qh = Tv + NW;
    unsigned short* Kh = Qh + NX;
    unsigned short* Vt = Kh + NX;

    float* ctx = (float*)d_out;
    float* attn = ctx + NX;

    cast_x_kernel<<<dim3(2048, 3), 256, 0, stream>>>(query, key, value, Xq, Xk, Xv);
    transpose_w_kernel<<<dim3(32, 32, 3), dim3(32, 8), 0, stream>>>(Wq, Wk, Wv, Tq, Tk, Tv);
    proj_gemm_kernel<<<dim3(8, 32, 3), 256, 0, stream>>>(Xq, Xk, Xv, Tq, Tk, Tv,
                                                         bq, bk, bv, Qh, Kh, Vt);
    attn_kernel<<<dim3(32, 32), 256, 0, stream>>>(Qh, Kh, Vt, ctx, attn);
}